// Round 6
// baseline (846.553 us; speedup 1.0000x reference)
//
#include <hip/hip_runtime.h>
#include <math.h>

#define NN 4
#define C 128          // inC == outC
#define DD 16
#define HH 64
#define WW 64
#define LL 512
#define EPSF 1e-8f
#define DHW (DD * HH * WW)

typedef unsigned short ushort_t;
typedef __attribute__((ext_vector_type(8)))  short short8;
typedef __attribute__((ext_vector_type(16))) float f32x16;

__device__ __forceinline__ ushort_t f2bf(float f) {
    unsigned u = __float_as_uint(f);
    unsigned r = (u + 0x7fffu + ((u >> 16) & 1u)) >> 16;
    return (ushort_t)r;
}
__device__ __forceinline__ float bf2f(ushort_t h) {
    return __uint_as_float(((unsigned)h) << 16);
}

// ---------------- style[n,c] = latent[n,:] . fc_w[c,:] + fc_b[c] ----------------
__global__ __launch_bounds__(64) void k_style(const float* __restrict__ latent,
                                              const float* __restrict__ fc_w,
                                              const float* __restrict__ fc_b,
                                              float* __restrict__ style) {
    int b = blockIdx.x;          // n*128 + c
    int n = b >> 7, c = b & 127;
    int lane = threadIdx.x;
    const float* lat = latent + n * LL;
    const float* w   = fc_w   + c * LL;
    float s = 0.f;
    for (int l = lane; l < LL; l += 64) s += lat[l] * w[l];
    #pragma unroll
    for (int off = 32; off; off >>= 1) s += __shfl_down(s, off);
    if (lane == 0) style[b] = s + fc_b[c];
}

// ---------------- s2[oc,ic] = sum_t weight[oc,ic,t]^2 ----------------
__global__ __launch_bounds__(128) void k_s2(const float* __restrict__ weight,
                                            float* __restrict__ s2) {
    int oc = blockIdx.x, ic = threadIdx.x;
    const float* src = weight + (oc * C + ic) * 27;
    float s = 0.f;
    #pragma unroll
    for (int t = 0; t < 27; ++t) { float v = src[t]; s += v * v; }
    s2[oc * C + ic] = s;
}

// ---------------- demod[n,oc] = rsqrt(sum_ic s2[oc,ic]*style[n,ic]^2 + eps) ------
__global__ __launch_bounds__(64) void k_demod(const float* __restrict__ s2,
                                              const float* __restrict__ style,
                                              float* __restrict__ demod) {
    int b = blockIdx.x;            // n*128 + oc
    int n = b >> 7, oc = b & 127;
    int lane = threadIdx.x;
    float s = 0.f;
    for (int ic = lane; ic < C; ic += 64) {
        float st = style[n * C + ic];
        s += s2[oc * C + ic] * st * st;
    }
    #pragma unroll
    for (int off = 32; off; off >>= 1) s += __shfl_down(s, off);
    if (lane == 0) demod[b] = rsqrtf(s + EPSF);
}

// ------- Wt[s=kdh*8+cc][part 2][kw 3][oc 128][i 16] (ushort bf16) -------
// part 0 = hi = bf16(w); part 1 = lo = bf16(w - hi)
__global__ __launch_bounds__(256) void k_wt(const float* __restrict__ w,
                                            ushort_t* __restrict__ Wt) {
    int b = blockIdx.x;            // 0..71 : kdh*8 + cc
    int kdh = b >> 3, cc = b & 7;
    int kd = kdh / 3, kh = kdh - 3 * kd;
    for (int e = threadIdx.x; e < 12288; e += 256) {
        int i  = e & 15;
        int oc = (e >> 4) & 127;
        int t  = e >> 11;          // part*3 + kw
        int part = t / 3, kw = t - 3 * part;
        int ic = cc * 16 + i;
        float v = w[(oc * C + ic) * 27 + kd * 9 + kh * 3 + kw];
        ushort_t hv = f2bf(v);
        ushort_t ov = (part == 0) ? hv : f2bf(v - bf2f(hv));
        Wt[(size_t)b * 12288 + e] = ov;
    }
}

// ---------------- main conv: implicit GEMM, bf16-split MFMA ----------------
// Block: (n, d, 2 h-rows) x 128 oc x 64 w. 4 waves, each 64oc x (1 row x 64 w)
// as 2x2 tiles of mfma_f32_32x32x16_bf16. 72 stages (9 kdh x 8 ic-chunks).
// A-fragments (weights) read DIRECTLY from global (L1/L2-resident, 1.77 MB
// shared across all blocks) -> no weight LDS, no global_load_lds, ONE barrier
// per stage with double-buffered x LDS.
__global__ __launch_bounds__(256, 2) void k_conv(
        const float* __restrict__ x,
        const ushort_t* __restrict__ Wt,
        const float* __restrict__ style,
        const float* __restrict__ demod,
        float* __restrict__ out) {

    __shared__ __align__(16) ushort_t xld[2][2][2][2][66][8]; // buf,part,row,icb,w',i  33792 B
    __shared__ float stl[C];
    __shared__ float dml[C];

    const int hb = blockIdx.x;     // 0..31
    const int d  = blockIdx.y;     // 0..15
    const int n  = blockIdx.z;     // 0..3
    const int h0 = hb * 2;
    const int tid  = threadIdx.x;
    const int lane = tid & 63;
    const int wv   = tid >> 6;     // wave 0..3
    const int wr   = wv >> 1;      // oc half
    const int wc   = wv & 1;       // h row
    const int l31  = lane & 31;
    const int kreg = lane >> 5;

    // staging thread mapping: (row, icb, w)
    const int srow = tid >> 7;
    const int sicb = (tid >> 6) & 1;
    const int sw   = tid & 63;

    if (tid < C)          stl[tid]     = style[n * C + tid];
    else if (tid < 2 * C) dml[tid - C] = demod[n * C + tid - C];
    if (tid < 32) {                // zero w-halo slots (image border), both buffers
        int buf  = tid >> 4, part = (tid >> 3) & 1, row = (tid >> 2) & 1,
            icb  = (tid >> 1) & 1, e = tid & 1;
        *(short8*)&xld[buf][part][row][icb][e ? 65 : 0][0] = (short8)0;
    }
    __syncthreads();   // stl visible for prologue split

    f32x16 acc[2][2] = {};

    // ---- prologue: stage 0 (kdh=0 -> kd=0,kh=0, cc=0) into buf 0 ----
    {
        const int zd = d - 1, zh = h0 - 1 + srow;
        const bool valid = ((unsigned)zd < DD) && ((unsigned)zh < HH);
        const float* base = x + ((((size_t)n * C + sicb * 8) * DD + zd) * HH + zh) * WW + sw;
        float xr[8];
        #pragma unroll
        for (int j = 0; j < 8; ++j) xr[j] = valid ? base[(size_t)j * DHW] : 0.f;
        float4 sa = *(float4*)&stl[sicb * 8];
        float4 sb = *(float4*)&stl[sicb * 8 + 4];
        float stv[8] = {sa.x, sa.y, sa.z, sa.w, sb.x, sb.y, sb.z, sb.w};
        short8 vh, vl;
        #pragma unroll
        for (int j = 0; j < 8; ++j) {
            float v = xr[j] * stv[j];
            ushort_t hv = f2bf(v);
            vh[j] = (short)hv;
            vl[j] = (short)f2bf(v - bf2f(hv));
        }
        *(short8*)&xld[0][0][srow][sicb][1 + sw][0] = vh;
        *(short8*)&xld[0][1][srow][sicb][1 + sw][0] = vl;
    }
    __syncthreads();

    for (int s = 0; s < 72; ++s) {
        const int cur = s & 1;
        const int s1  = (s < 71) ? s + 1 : 71;

        // ---- issue x global loads for stage s1 (latency hidden by compute) ----
        const int kdh1 = s1 >> 3, cc1 = s1 & 7;
        const int kd1  = kdh1 / 3;
        const int zd   = d + kd1 - 1;
        const int zh   = h0 + (kdh1 - 3 * kd1) - 1 + srow;
        const bool valid = ((unsigned)zd < DD) && ((unsigned)zh < HH);
        const float* base = x + ((((size_t)n * C + cc1 * 16 + sicb * 8) * DD + zd) * HH + zh) * WW + sw;
        float xr[8];
        #pragma unroll
        for (int j = 0; j < 8; ++j) xr[j] = valid ? base[(size_t)j * DHW] : 0.f;

        // ---- compute stage s: A from global (L1/L2), B from xld[cur] ----
        {
            const ushort_t* gWs = Wt + (size_t)s * 12288;
            short8 ah[3][2], al[3][2];
            #pragma unroll
            for (int kw = 0; kw < 3; ++kw)
                #pragma unroll
                for (int o = 0; o < 2; ++o) {
                    const ushort_t* ab = gWs + (kw * C + wr * 64 + o * 32 + l31) * 16 + kreg * 8;
                    ah[kw][o] = *(const short8*)ab;
                    al[kw][o] = *(const short8*)(ab + 3 * C * 16);
                }
            #pragma unroll
            for (int kw = 0; kw < 3; ++kw) {
                short8 b0[2], b1[2];
                #pragma unroll
                for (int p = 0; p < 2; ++p) {
                    const int wpos = p * 32 + l31 + kw;
                    b0[p] = *(const short8*)&xld[cur][0][wc][kreg][wpos][0];
                    b1[p] = *(const short8*)&xld[cur][1][wc][kreg][wpos][0];
                }
                #pragma unroll
                for (int o = 0; o < 2; ++o)
                    #pragma unroll
                    for (int p = 0; p < 2; ++p) {
                        acc[o][p] = __builtin_amdgcn_mfma_f32_32x32x16_bf16(
                                        ah[kw][o], b0[p], acc[o][p], 0, 0, 0);
                        acc[o][p] = __builtin_amdgcn_mfma_f32_32x32x16_bf16(
                                        ah[kw][o], b1[p], acc[o][p], 0, 0, 0);
                        acc[o][p] = __builtin_amdgcn_mfma_f32_32x32x16_bf16(
                                        al[kw][o], b0[p], acc[o][p], 0, 0, 0);
                    }
            }
        }

        // ---- split + write x(s1) into the OTHER buffer (no read/write hazard) ----
        {
            float4 sa = *(float4*)&stl[cc1 * 16 + sicb * 8];
            float4 sb = *(float4*)&stl[cc1 * 16 + sicb * 8 + 4];
            float stv[8] = {sa.x, sa.y, sa.z, sa.w, sb.x, sb.y, sb.z, sb.w};
            short8 vh, vl;
            #pragma unroll
            for (int j = 0; j < 8; ++j) {
                float v = xr[j] * stv[j];
                ushort_t hv = f2bf(v);
                vh[j] = (short)hv;
                vl[j] = (short)f2bf(v - bf2f(hv));
            }
            *(short8*)&xld[cur ^ 1][0][srow][sicb][1 + sw][0] = vh;
            *(short8*)&xld[cur ^ 1][1][srow][sicb][1 + sw][0] = vl;
        }

        // ---- single barrier per stage. vmcnt is already drained by use:
        // A-frags consumed by MFMA, x-prefetch consumed by the split above,
        // so __syncthreads' full waitcnt costs ~nothing here and is race-safe.
        __syncthreads();
    }

    // ---- epilogue: demod scale + store ----
    const int h = h0 + wc;
    #pragma unroll
    for (int o = 0; o < 2; ++o) {
        #pragma unroll
        for (int r = 0; r < 16; ++r) {
            const int ocrow = (r & 3) + 8 * (r >> 2) + 4 * kreg;
            const int oc = wr * 64 + o * 32 + ocrow;
            const float dm = dml[oc];
            #pragma unroll
            for (int p = 0; p < 2; ++p) {
                const int wq = p * 32 + l31;
                out[((((size_t)n * C + oc) * DD + d) * HH + h) * WW + wq] =
                    acc[o][p][r] * dm;
            }
        }
    }
}

extern "C" void kernel_launch(void* const* d_in, const int* in_sizes, int n_in,
                              void* d_out, int out_size, void* d_ws, size_t ws_size,
                              hipStream_t stream) {
    const float* x      = (const float*)d_in[0];
    const float* latent = (const float*)d_in[1];
    const float* weight = (const float*)d_in[2];
    const float* fc_w   = (const float*)d_in[3];
    const float* fc_b   = (const float*)d_in[4];
    float* out = (float*)d_out;

    float* style = (float*)d_ws;                    // 512 f32
    float* demod = style + 512;                     // 512 f32
    float* s2    = demod + 512;                     // 16384 f32
    ushort_t* Wt = (ushort_t*)(s2 + 16384);         // 884736 ushort (~1.77 MB)

    hipLaunchKernelGGL(k_style, dim3(NN * C), dim3(64), 0, stream,
                       latent, fc_w, fc_b, style);
    hipLaunchKernelGGL(k_s2,    dim3(C), dim3(C), 0, stream, weight, s2);
    hipLaunchKernelGGL(k_wt,    dim3(72), dim3(256), 0, stream, weight, Wt);
    hipLaunchKernelGGL(k_demod, dim3(NN * C), dim3(64), 0, stream,
                       s2, style, demod);
    hipLaunchKernelGGL(k_conv,  dim3(32, DD, NN), dim3(256), 0, stream,
                       x, Wt, style, demod, out);
}